// Round 1
// baseline (57.098 us; speedup 1.0000x reference)
//
#include <hip/hip_runtime.h>

// QuantumSelfAttention: closed-form collapse of the 10-qubit staircase circuit.
//
// Reference circuit per sample t:
//   |psi> = CU(8,9)...CU(1,2)CU(0,1) * prod_j RX(2*theta_j) |0..0>,
//   theta_j = (x_j + rot_j)/2,  CU(i,i+1) = |0><0|_i (x) I + |1><1|_i (x) R(ent_i/2),
//   R(phi) = [[cos,-sin],[sin,cos]] (real),  output_j = <Z_j>.
//
// Because (a) Z_j commutes with CU(j,j+1), (b) qubit j+1 is in a product state
// until CU(j,j+1) fires, and (c) the control trace only sees the DIAGONAL of the
// control qubit's reduced density matrix (and the RX coherence is purely
// imaginary, cancelling under the real rotation), <Z_j> obeys a scalar Markov
// recursion:
//   q_0 = cos(x_0 + r_0)
//   q_j = cos(x_j + r_j) * (1 + sp2_{j-1} * (q_{j-1} - 1)),  sp2_i = sin^2(ent_i/2)
// Verified by hand against the reference at n=2. O(n) per sample instead of O(n*2^n).

#define N_Q 10

__global__ __launch_bounds__(64) void qsa_kernel(
    const float* __restrict__ x,     // (T, 10)
    const float* __restrict__ rot,   // (10,)
    const float* __restrict__ ent,   // (9,)
    float* __restrict__ out,         // (T, 10)
    int T)
{
    int t = blockIdx.x * blockDim.x + threadIdx.x;
    if (t >= T) return;

    // Broadcast params: same address across all lanes -> scalar/L1 cached.
    float r[N_Q];
#pragma unroll
    for (int j = 0; j < N_Q; ++j) r[j] = rot[j];

    float sp2[N_Q - 1];
#pragma unroll
    for (int i = 0; i < N_Q - 1; ++i) {
        float s = __sinf(0.5f * ent[i]);
        sp2[i] = s * s;
    }

    // Per-thread input row: byte offset t*40, 8-aligned -> float2 loads OK.
    const float2* xp = reinterpret_cast<const float2*>(x + (size_t)t * N_Q);
    float xv[N_Q];
#pragma unroll
    for (int i = 0; i < N_Q / 2; ++i) {
        float2 v = xp[i];
        xv[2 * i]     = v.x;
        xv[2 * i + 1] = v.y;
    }

    float o[N_Q];
    float q = __cosf(xv[0] + r[0]);
    o[0] = q;
#pragma unroll
    for (int j = 1; j < N_Q; ++j) {
        float d = __cosf(xv[j] + r[j]);
        // q = d * ((1 - sp2) + sp2 * q) = d * (1 + sp2*(q-1))
        q = d * fmaf(sp2[j - 1], q - 1.0f, 1.0f);
        o[j] = q;
    }

    float2* op = reinterpret_cast<float2*>(out + (size_t)t * N_Q);
#pragma unroll
    for (int i = 0; i < N_Q / 2; ++i) {
        op[i] = make_float2(o[2 * i], o[2 * i + 1]);
    }
}

extern "C" void kernel_launch(void* const* d_in, const int* in_sizes, int n_in,
                              void* d_out, int out_size, void* d_ws, size_t ws_size,
                              hipStream_t stream)
{
    const float* x   = (const float*)d_in[0];
    const float* rot = (const float*)d_in[1];
    const float* ent = (const float*)d_in[2];
    float* out = (float*)d_out;

    int T = in_sizes[0] / N_Q;  // 16 * 1024 = 16384
    const int block = 64;
    int grid = (T + block - 1) / block;  // 256 blocks -> ~1 wave per CU
    hipLaunchKernelGGL(qsa_kernel, dim3(grid), dim3(block), 0, stream,
                       x, rot, ent, out, T);
}